// Round 3
// baseline (99.789 us; speedup 1.0000x reference)
//
#include <hip/hip_runtime.h>

#define B_   16
#define C_   256
#define HW_  4096
#define DQK  131072     // 32*4096, q/k feature dim per batch
#define DV   1048576    // 256*4096, v feature dim per batch

using bf16x8  = __attribute__((ext_vector_type(8))) __bf16;
using ushort8 = __attribute__((ext_vector_type(8))) unsigned short;
using u16x4   = __attribute__((ext_vector_type(4))) unsigned short;
using f32x4   = __attribute__((ext_vector_type(4))) float;

static __device__ __forceinline__ unsigned short f2bf(float f) {
    union { float f; unsigned u; } v; v.f = f;
    unsigned r = v.u + 0x7FFFu + ((v.u >> 16) & 1u);
    return (unsigned short)(r >> 16);
}
static __device__ __forceinline__ float bf2f(unsigned short h) {
    union { unsigned u; float f; } v; v.u = ((unsigned)h) << 16;
    return v.f;
}

// ---------------- pack weights: Wh/Wl = hi/lo split of [wq;wk] (64x256), Wv bf16 (256x256)
__global__ __launch_bounds__(256) void k_pack(const float* wq, const float* wk, const float* wv,
                                              unsigned short* Wh, unsigned short* Wl, unsigned short* Wv) {
    int idx = blockIdx.x * 256 + threadIdx.x;   // 81920 total
    if (idx < 16384) {
        float f = (idx < 8192) ? wq[idx] : wk[idx - 8192];
        unsigned short hi = f2bf(f);
        Wh[idx] = hi;
        Wl[idx] = f2bf(f - bf2f(hi));
    } else {
        int i = idx - 16384;
        Wv[i] = f2bf(wv[i]);
    }
}

// ---------------- qk GEMM, split-bf16 precision: rows 0..31 q, 32..63 k; fp32 out
// B-staging LDS writes XOR-swizzled on col-group to kill 16-way bank conflicts.
__global__ __launch_bounds__(256) void k_gemm_qk(const unsigned short* __restrict__ Wh,
                                                 const unsigned short* __restrict__ Wl,
                                                 const float* __restrict__ x,
                                                 const float* __restrict__ bq, const float* __restrict__ bk,
                                                 float* __restrict__ QF, float* __restrict__ KF) {
    __shared__ __align__(16) unsigned short Ah[64][40], Al[64][40];
    __shared__ __align__(16) unsigned short Bh[128][40], Bl[128][40];
    int b  = blockIdx.y;
    int n0 = blockIdx.x * 128;
    int t = threadIdx.x;
    int lane = t & 63, wid = t >> 6;
    int wm = wid >> 1, wn = wid & 1;
    int lr = lane & 15, kg = lane >> 4;

    const float* xb = x + (size_t)b * DV;
    int am = t >> 2, akq = (t & 3) * 8;
    int bkr = t >> 3, bnq = (t & 7) * 16;
    int swz_w = (t & 3) << 3;                 // == ((row>>4)&3)<<3 for all rows this thread writes
    int colw  = bkr ^ swz_w;

    f32x4 acc[2][4];
    for (int mi = 0; mi < 2; mi++)
        for (int ni = 0; ni < 4; ni++) acc[mi][ni] = (f32x4){0.f, 0.f, 0.f, 0.f};

    for (int kk = 0; kk < 8; kk++) {
        int k0 = kk * 32;
        *(ushort8*)&Ah[am][akq] = *(const ushort8*)(Wh + (size_t)am * 256 + k0 + akq);
        *(ushort8*)&Al[am][akq] = *(const ushort8*)(Wl + (size_t)am * 256 + k0 + akq);
        const float* srcb = xb + (size_t)(k0 + bkr) * HW_ + n0 + bnq;
        for (int e4 = 0; e4 < 4; e4++) {
            f32x4 v = *(const f32x4*)(srcb + e4 * 4);
            for (int e = 0; e < 4; e++) {
                float f = v[e];
                unsigned short hi = f2bf(f);
                int row = bnq + e4 * 4 + e;
                Bh[row][colw] = hi;
                Bl[row][colw] = f2bf(f - bf2f(hi));
            }
        }
        __syncthreads();
        bf16x8 ah[2], al[2], bh[4], bl[4];
        for (int mi = 0; mi < 2; mi++) {
            ah[mi] = *(const bf16x8*)&Ah[wm * 32 + mi * 16 + lr][kg * 8];
            al[mi] = *(const bf16x8*)&Al[wm * 32 + mi * 16 + lr][kg * 8];
        }
        for (int ni = 0; ni < 4; ni++) {
            int row = wn * 64 + ni * 16 + lr;
            int cg  = (kg ^ ((wn * 4 + ni) & 3)) * 8;     // read-side un-swizzle
            bh[ni] = *(const bf16x8*)&Bh[row][cg];
            bl[ni] = *(const bf16x8*)&Bl[row][cg];
        }
        for (int mi = 0; mi < 2; mi++)
            for (int ni = 0; ni < 4; ni++) {
                acc[mi][ni] = __builtin_amdgcn_mfma_f32_16x16x32_bf16(ah[mi], bh[ni], acc[mi][ni], 0, 0, 0);
                acc[mi][ni] = __builtin_amdgcn_mfma_f32_16x16x32_bf16(ah[mi], bl[ni], acc[mi][ni], 0, 0, 0);
                acc[mi][ni] = __builtin_amdgcn_mfma_f32_16x16x32_bf16(al[mi], bh[ni], acc[mi][ni], 0, 0, 0);
            }
        __syncthreads();
    }
    for (int mi = 0; mi < 2; mi++) {
        int mbase = wm * 32 + mi * 16 + kg * 4;
        for (int i = 0; i < 4; i++) {
            int m = mbase + i;
            float bias = (m < 32) ? bq[m] : bk[m - 32];
            for (int ni = 0; ni < 4; ni++) {
                int n = n0 + wn * 64 + ni * 16 + lr;
                float val = acc[mi][ni][i] + bias;
                if (m < 32) QF[(size_t)b * DQK + (size_t)m * HW_ + n] = val;
                else        KF[(size_t)b * DQK + (size_t)(m - 32) * HW_ + n] = val;
            }
        }
    }
}

// ---------------- scores v2: 256 blocks, each owns a 512-elem d-slice for ALL 16 batches.
// Stages q,k slices in LDS once (1x read amplification), computes 128 pair-partials.
__global__ __launch_bounds__(256) void k_scores2(const float* __restrict__ QF, const float* __restrict__ KF,
                                                 float* __restrict__ Sp) {
    __shared__ float Ql[16][520], Kl[16][520];   // +8 pad: spreads banks across b
    int s = blockIdx.x;                          // 0..255 : d-slice [s*512, s*512+512)
    int m = s >> 3, off = (s & 7) * 512;
    int t = threadIdx.x;
    for (int b = 0; b < 16; b++) {
        const float* qs = QF + (size_t)b * DQK + (size_t)m * HW_ + off;
        const float* ks = KF + (size_t)b * DQK + (size_t)m * HW_ + off;
        Ql[b][t]       = qs[t];
        Ql[b][t + 256] = qs[t + 256];
        Kl[b][t]       = ks[t];
        Kl[b][t + 256] = ks[t + 256];
    }
    __syncthreads();
    int p = t >> 1, h = t & 1;                   // 2 threads per pair
    int b = p >> 3, j = p & 7;
    int hb = b >> 2, wb = b & 3;
    int bp = (j < 4) ? (j * 4 + wb) : (hb * 4 + (j - 4));
    const f32x4* q4 = (const f32x4*)&Ql[b][h * 256];
    const f32x4* k4 = (const f32x4*)&Kl[bp][h * 256];
    f32x4 a4 = (f32x4){0.f, 0.f, 0.f, 0.f};
    for (int i = 0; i < 64; i++) a4 += q4[i] * k4[i];
    float sres = a4[0] + a4[1] + a4[2] + a4[3];
    sres += __shfl_xor(sres, 1);
    if (h == 0) Sp[(size_t)p * 256 + s] = sres;  // layout [pair][slice]
}

// ---------------- reduce slices + softmax + fold gamma -> M [0..255] + rowsum [256..271]
__global__ void k_softmax2(const float* __restrict__ Sp, const float* __restrict__ gamma,
                           float* __restrict__ Mm) {
    __shared__ float SS[128];
    int t = threadIdx.x;                         // 128 threads
    const f32x4* s4 = (const f32x4*)(Sp + (size_t)t * 256);
    f32x4 a = (f32x4){0.f, 0.f, 0.f, 0.f};
    for (int i = 0; i < 64; i++) a += s4[i];
    SS[t] = a[0] + a[1] + a[2] + a[3];
    __syncthreads();
    if (t < 16) {
        int b = t, h = b >> 2, w = b & 3;
        float e[8];
        for (int j = 0; j < 8; j++) e[j] = SS[b * 8 + j];
        e[h] = -INFINITY;                        // masked diagonal of eH
        float mx = e[0];
        for (int j = 1; j < 8; j++) mx = fmaxf(mx, e[j]);
        float aa[8], sum = 0.f;
        for (int j = 0; j < 8; j++) { aa[j] = expf(e[j] - mx); sum += aa[j]; }
        float inv = 1.0f / sum;
        float g = gamma[0];
        float row[16];
        for (int c = 0; c < 16; c++) row[c] = 0.f;
        for (int gg = 0; gg < 4; gg++) if (gg != h) row[gg * 4 + w] += aa[gg] * inv;     // eH partners
        for (int gg = 0; gg < 4; gg++) row[h * 4 + gg] += aa[4 + gg] * inv;              // eW partners
        for (int c = 0; c < 16; c++) Mm[b * 16 + c] = row[c] * g;
        Mm[256 + b] = g;                         // rowsum of M (softmax rows sum to 1)
    }
}

// ---------------- mix + transpose + convert: Xm chunked [b][cb][p][32c] bf16
// Xm[b][cb][p][ci] = sum_bp M[b][bp] * x[bp][cb*32+ci][p]
__global__ __launch_bounds__(256) void k_mix(const float* __restrict__ Mm, const float* __restrict__ x,
                                             unsigned short* __restrict__ Xm) {
    __shared__ float Ms[256];
    __shared__ unsigned short T[16][32][36];
    int t = threadIdx.x;
    int p0 = blockIdx.x * 32, cb = blockIdx.y, c0 = cb * 32;
    Ms[t] = Mm[t];

    int c_l = t >> 3, p4 = t & 7;          // phase A: thread owns (ci=c_l, p = p4*4..p4*4+3)
    f32x4 in4[16];
    for (int bp = 0; bp < 16; bp++)
        in4[bp] = *(const f32x4*)(x + (size_t)bp * DV + (size_t)(c0 + c_l) * HW_ + p0 + p4 * 4);
    __syncthreads();
    for (int b = 0; b < 16; b++) {
        f32x4 acc = (f32x4){0.f, 0.f, 0.f, 0.f};
        for (int bp = 0; bp < 16; bp++) {
            float wgt = Ms[b * 16 + bp];
            acc += wgt * in4[bp];
        }
        for (int e = 0; e < 4; e++) T[b][p4 * 4 + e][c_l] = f2bf(acc[e]);
    }
    __syncthreads();
    int p_l = t >> 3, cq = t & 7;          // phase B: chunk-contiguous writeout (512B/wave)
    for (int b = 0; b < 16; b++) {
        u16x4 v = *(const u16x4*)&T[b][p_l][cq * 4];
        *(u16x4*)(Xm + ((size_t)(b * 8 + cb) * HW_ + p0 + p_l) * 32 + cq * 4) = v;
    }
}

// ---------------- v GEMM + bias + residual, BK=64, chunked-Xm B reads
// out[b][m][n] = sum_k Wv[m][k]*Xm[b][n][k] + rs[b]*bv[m] + x[b][m][n]
__global__ __launch_bounds__(256) void k_gemm_v_res(const unsigned short* __restrict__ Wv,
                                                    const unsigned short* __restrict__ Xm,
                                                    const float* __restrict__ bv,
                                                    const float* __restrict__ MmRs,
                                                    const float* __restrict__ x,
                                                    float* __restrict__ out) {
    __shared__ __align__(16) unsigned short As[64][72];
    __shared__ __align__(16) unsigned short Bs[128][72];
    int b  = blockIdx.z;
    int m0 = blockIdx.y * 64;
    int n0 = blockIdx.x * 128;
    int t = threadIdx.x;
    int lane = t & 63, wid = t >> 6;
    int wm = wid >> 1, wn = wid & 1;
    int lr = lane & 15, kg = lane >> 4;

    int am = t >> 2, aq = (t & 3) * 16;
    int bn = t >> 1, half = t & 1;

    f32x4 acc[2][4];
    for (int mi = 0; mi < 2; mi++)
        for (int ni = 0; ni < 4; ni++) acc[mi][ni] = (f32x4){0.f, 0.f, 0.f, 0.f};

    for (int kk = 0; kk < 4; kk++) {
        int k0 = kk * 64;
        *(ushort8*)&As[am][aq]     = *(const ushort8*)(Wv + (size_t)(m0 + am) * 256 + k0 + aq);
        *(ushort8*)&As[am][aq + 8] = *(const ushort8*)(Wv + (size_t)(m0 + am) * 256 + k0 + aq + 8);
        const unsigned short* c0p = Xm + ((size_t)(b * 8 + kk * 2)     * HW_ + n0 + bn) * 32 + half * 16;
        const unsigned short* c1p = Xm + ((size_t)(b * 8 + kk * 2 + 1) * HW_ + n0 + bn) * 32 + half * 16;
        *(ushort8*)&Bs[bn][half * 16]          = *(const ushort8*)(c0p);
        *(ushort8*)&Bs[bn][half * 16 + 8]      = *(const ushort8*)(c0p + 8);
        *(ushort8*)&Bs[bn][32 + half * 16]     = *(const ushort8*)(c1p);
        *(ushort8*)&Bs[bn][32 + half * 16 + 8] = *(const ushort8*)(c1p + 8);
        __syncthreads();
        for (int ks = 0; ks < 2; ks++) {
            bf16x8 a[2], bb[4];
            for (int mi = 0; mi < 2; mi++) a[mi]  = *(const bf16x8*)&As[wm * 32 + mi * 16 + lr][ks * 32 + kg * 8];
            for (int ni = 0; ni < 4; ni++) bb[ni] = *(const bf16x8*)&Bs[wn * 64 + ni * 16 + lr][ks * 32 + kg * 8];
            for (int mi = 0; mi < 2; mi++)
                for (int ni = 0; ni < 4; ni++)
                    acc[mi][ni] = __builtin_amdgcn_mfma_f32_16x16x32_bf16(a[mi], bb[ni], acc[mi][ni], 0, 0, 0);
        }
        __syncthreads();
    }
    float rs_b = MmRs[256 + b];
    for (int mi = 0; mi < 2; mi++) {
        int mbase = m0 + wm * 32 + mi * 16 + kg * 4;
        for (int i = 0; i < 4; i++) {
            int m = mbase + i;
            float bias = rs_b * bv[m];
            for (int ni = 0; ni < 4; ni++) {
                int n = n0 + wn * 64 + ni * 16 + lr;
                size_t idx = (size_t)b * DV + (size_t)m * HW_ + n;
                out[idx] = acc[mi][ni][i] + bias + x[idx];
            }
        }
    }
}

extern "C" void kernel_launch(void* const* d_in, const int* in_sizes, int n_in,
                              void* d_out, int out_size, void* d_ws, size_t ws_size,
                              hipStream_t stream) {
    (void)in_sizes; (void)n_in; (void)out_size; (void)ws_size;
    const float* x     = (const float*)d_in[0];
    const float* wq    = (const float*)d_in[1];
    const float* bq    = (const float*)d_in[2];
    const float* wk    = (const float*)d_in[3];
    const float* bk    = (const float*)d_in[4];
    const float* wv    = (const float*)d_in[5];
    const float* bv    = (const float*)d_in[6];
    const float* gamma = (const float*)d_in[7];

    char* ws = (char*)d_ws;
    // ws layout (bytes): Wh 32768 | Wl 32768 | Wv 131072 | QF 8388608 | KF 8388608 | Xm 33554432
    // Aliases (lifetime-disjoint): Mm@0 (Wh dead after qk); Sp@Xm-start (dead before mix writes).
    unsigned short* Wh = (unsigned short*)(ws + 0);
    unsigned short* Wl = (unsigned short*)(ws + 32768);
    unsigned short* Wv = (unsigned short*)(ws + 65536);
    float*          QF = (float*)(ws + 196608);
    float*          KF = (float*)(ws + 8585216);
    unsigned short* Xm = (unsigned short*)(ws + 16973824);   // 33554432 bytes -> total 50528256
    float*          Sp = (float*)(ws + 16973824);            // 128 KB, aliases Xm (ordered before)
    float*          Mm = (float*)(ws + 0);                   // aliases Wh (dead by then)
    float*          vo = (float*)d_out;

    k_pack       <<<320, 256, 0, stream>>>(wq, wk, wv, Wh, Wl, Wv);
    k_gemm_qk    <<<dim3(32, 16), 256, 0, stream>>>(Wh, Wl, x, bq, bk, QF, KF);
    k_scores2    <<<256, 256, 0, stream>>>(QF, KF, Sp);
    k_softmax2   <<<1, 128, 0, stream>>>(Sp, gamma, Mm);
    k_mix        <<<dim3(128, 8), 256, 0, stream>>>(Mm, x, Xm);
    k_gemm_v_res <<<dim3(32, 4, 16), 256, 0, stream>>>(Wv, Xm, bv, Mm, x, vo);
}

// Round 4
// 92.395 us; speedup vs baseline: 1.0800x; 1.0800x over previous
//
#include <hip/hip_runtime.h>

#define B_   16
#define C_   256
#define HW_  4096
#define DQK  131072     // 32*4096, q/k feature dim per batch
#define DV   1048576    // 256*4096, v feature dim per batch

using bf16x8  = __attribute__((ext_vector_type(8))) __bf16;
using ushort8 = __attribute__((ext_vector_type(8))) unsigned short;
using u16x4   = __attribute__((ext_vector_type(4))) unsigned short;
using f32x4   = __attribute__((ext_vector_type(4))) float;

static __device__ __forceinline__ unsigned short f2bf(float f) {
    union { float f; unsigned u; } v; v.f = f;
    unsigned r = v.u + 0x7FFFu + ((v.u >> 16) & 1u);
    return (unsigned short)(r >> 16);
}
static __device__ __forceinline__ float bf2f(unsigned short h) {
    union { unsigned u; float f; } v; v.u = ((unsigned)h) << 16;
    return v.f;
}

// ---------------- pack weights: Wh/Wl = hi/lo split of [wq;wk] (64x256);
// Wv bf16 PRE-FRAGMENTED: dst(m,c) = (m>>4)*4096 + (c>>3)*128 + (m&15)*8 + (c&7)
__global__ __launch_bounds__(256) void k_pack(const float* wq, const float* wk, const float* wv,
                                              unsigned short* Wh, unsigned short* Wl, unsigned short* Wv) {
    int idx = blockIdx.x * 256 + threadIdx.x;   // 81920 total
    if (idx < 16384) {
        float f = (idx < 8192) ? wq[idx] : wk[idx - 8192];
        unsigned short hi = f2bf(f);
        Wh[idx] = hi;
        Wl[idx] = f2bf(f - bf2f(hi));
    } else {
        int i = idx - 16384;                    // destination-linear (coalesced writes)
        int mt = i >> 12, kt = (i >> 7) & 31, lr = (i >> 3) & 15, j = i & 7;
        int m = mt * 16 + lr, c = kt * 8 + j;
        Wv[i] = f2bf(wv[m * 256 + c]);
    }
}

// ---------------- qk GEMM, split-bf16 precision: rows 0..31 q, 32..63 k; fp32 out
// B-staging LDS writes XOR-swizzled on col-group to kill 16-way bank conflicts.
__global__ __launch_bounds__(256) void k_gemm_qk(const unsigned short* __restrict__ Wh,
                                                 const unsigned short* __restrict__ Wl,
                                                 const float* __restrict__ x,
                                                 const float* __restrict__ bq, const float* __restrict__ bk,
                                                 float* __restrict__ QF, float* __restrict__ KF) {
    __shared__ __align__(16) unsigned short Ah[64][40], Al[64][40];
    __shared__ __align__(16) unsigned short Bh[128][40], Bl[128][40];
    int b  = blockIdx.y;
    int n0 = blockIdx.x * 128;
    int t = threadIdx.x;
    int lane = t & 63, wid = t >> 6;
    int wm = wid >> 1, wn = wid & 1;
    int lr = lane & 15, kg = lane >> 4;

    const float* xb = x + (size_t)b * DV;
    int am = t >> 2, akq = (t & 3) * 8;
    int bkr = t >> 3, bnq = (t & 7) * 16;
    int swz_w = (t & 3) << 3;                 // == ((row>>4)&3)<<3 for all rows this thread writes
    int colw  = bkr ^ swz_w;

    f32x4 acc[2][4];
    for (int mi = 0; mi < 2; mi++)
        for (int ni = 0; ni < 4; ni++) acc[mi][ni] = (f32x4){0.f, 0.f, 0.f, 0.f};

    for (int kk = 0; kk < 8; kk++) {
        int k0 = kk * 32;
        *(ushort8*)&Ah[am][akq] = *(const ushort8*)(Wh + (size_t)am * 256 + k0 + akq);
        *(ushort8*)&Al[am][akq] = *(const ushort8*)(Wl + (size_t)am * 256 + k0 + akq);
        const float* srcb = xb + (size_t)(k0 + bkr) * HW_ + n0 + bnq;
        for (int e4 = 0; e4 < 4; e4++) {
            f32x4 v = *(const f32x4*)(srcb + e4 * 4);
            for (int e = 0; e < 4; e++) {
                float f = v[e];
                unsigned short hi = f2bf(f);
                int row = bnq + e4 * 4 + e;
                Bh[row][colw] = hi;
                Bl[row][colw] = f2bf(f - bf2f(hi));
            }
        }
        __syncthreads();
        bf16x8 ah[2], al[2], bh[4], bl[4];
        for (int mi = 0; mi < 2; mi++) {
            ah[mi] = *(const bf16x8*)&Ah[wm * 32 + mi * 16 + lr][kg * 8];
            al[mi] = *(const bf16x8*)&Al[wm * 32 + mi * 16 + lr][kg * 8];
        }
        for (int ni = 0; ni < 4; ni++) {
            int row = wn * 64 + ni * 16 + lr;
            int cg  = (kg ^ ((wn * 4 + ni) & 3)) * 8;     // read-side un-swizzle
            bh[ni] = *(const bf16x8*)&Bh[row][cg];
            bl[ni] = *(const bf16x8*)&Bl[row][cg];
        }
        for (int mi = 0; mi < 2; mi++)
            for (int ni = 0; ni < 4; ni++) {
                acc[mi][ni] = __builtin_amdgcn_mfma_f32_16x16x32_bf16(ah[mi], bh[ni], acc[mi][ni], 0, 0, 0);
                acc[mi][ni] = __builtin_amdgcn_mfma_f32_16x16x32_bf16(ah[mi], bl[ni], acc[mi][ni], 0, 0, 0);
                acc[mi][ni] = __builtin_amdgcn_mfma_f32_16x16x32_bf16(al[mi], bh[ni], acc[mi][ni], 0, 0, 0);
            }
        __syncthreads();
    }
    for (int mi = 0; mi < 2; mi++) {
        int mbase = wm * 32 + mi * 16 + kg * 4;
        for (int i = 0; i < 4; i++) {
            int m = mbase + i;
            float bias = (m < 32) ? bq[m] : bk[m - 32];
            for (int ni = 0; ni < 4; ni++) {
                int n = n0 + wn * 64 + ni * 16 + lr;
                float val = acc[mi][ni][i] + bias;
                if (m < 32) QF[(size_t)b * DQK + (size_t)m * HW_ + n] = val;
                else        KF[(size_t)b * DQK + (size_t)(m - 32) * HW_ + n] = val;
            }
        }
    }
}

// ---------------- scores v2: 256 blocks, each owns a 512-elem d-slice for ALL 16 batches.
__global__ __launch_bounds__(256) void k_scores2(const float* __restrict__ QF, const float* __restrict__ KF,
                                                 float* __restrict__ Sp) {
    __shared__ float Ql[16][520], Kl[16][520];   // +8 pad: spreads banks across b
    int s = blockIdx.x;                          // 0..255 : d-slice [s*512, s*512+512)
    int m = s >> 3, off = (s & 7) * 512;
    int t = threadIdx.x;
    for (int b = 0; b < 16; b++) {
        const float* qs = QF + (size_t)b * DQK + (size_t)m * HW_ + off;
        const float* ks = KF + (size_t)b * DQK + (size_t)m * HW_ + off;
        Ql[b][t]       = qs[t];
        Ql[b][t + 256] = qs[t + 256];
        Kl[b][t]       = ks[t];
        Kl[b][t + 256] = ks[t + 256];
    }
    __syncthreads();
    int p = t >> 1, h = t & 1;                   // 2 threads per pair
    int b = p >> 3, j = p & 7;
    int hb = b >> 2, wb = b & 3;
    int bp = (j < 4) ? (j * 4 + wb) : (hb * 4 + (j - 4));
    const f32x4* q4 = (const f32x4*)&Ql[b][h * 256];
    const f32x4* k4 = (const f32x4*)&Kl[bp][h * 256];
    f32x4 a4 = (f32x4){0.f, 0.f, 0.f, 0.f};
    for (int i = 0; i < 64; i++) a4 += q4[i] * k4[i];
    float sres = a4[0] + a4[1] + a4[2] + a4[3];
    sres += __shfl_xor(sres, 1);
    if (h == 0) Sp[(size_t)p * 256 + s] = sres;  // layout [pair][slice]
}

// ---------------- reduce slices + softmax + fold gamma -> M [0..255] + rowsum [256..271]
__global__ void k_softmax2(const float* __restrict__ Sp, const float* __restrict__ gamma,
                           float* __restrict__ Mm) {
    __shared__ float SS[128];
    int t = threadIdx.x;                         // 128 threads
    const f32x4* s4 = (const f32x4*)(Sp + (size_t)t * 256);
    f32x4 a = (f32x4){0.f, 0.f, 0.f, 0.f};
    for (int i = 0; i < 64; i++) a += s4[i];
    SS[t] = a[0] + a[1] + a[2] + a[3];
    __syncthreads();
    if (t < 16) {
        int b = t, h = b >> 2, w = b & 3;
        float e[8];
        for (int j = 0; j < 8; j++) e[j] = SS[b * 8 + j];
        e[h] = -INFINITY;                        // masked diagonal of eH
        float mx = e[0];
        for (int j = 1; j < 8; j++) mx = fmaxf(mx, e[j]);
        float aa[8], sum = 0.f;
        for (int j = 0; j < 8; j++) { aa[j] = expf(e[j] - mx); sum += aa[j]; }
        float inv = 1.0f / sum;
        float g = gamma[0];
        float row[16];
        for (int c = 0; c < 16; c++) row[c] = 0.f;
        for (int gg = 0; gg < 4; gg++) if (gg != h) row[gg * 4 + w] += aa[gg] * inv;     // eH partners
        for (int gg = 0; gg < 4; gg++) row[h * 4 + gg] += aa[4 + gg] * inv;              // eW partners
        for (int c = 0; c < 16; c++) Mm[b * 16 + c] = row[c] * g;
        Mm[256 + b] = g;                         // rowsum of M (softmax rows sum to 1)
    }
}

// ---------------- mix + transpose + convert, PRE-FRAGMENTED output:
// Xm addr(b,p,c) = b*DV + (p>>4)*4096 + (c>>3)*128 + (p&15)*8 + (c&7); value = sum_bp M[b][bp]*x[bp][c][p]
__global__ __launch_bounds__(256) void k_mix(const float* __restrict__ Mm, const float* __restrict__ x,
                                             unsigned short* __restrict__ Xm) {
    __shared__ float Ms[256];
    __shared__ unsigned short T[16][32][36];     // [b][p][c]
    int t = threadIdx.x;
    int p0 = blockIdx.x * 32, c0 = blockIdx.y * 32;
    Ms[t] = Mm[t];

    int c_l = t >> 3, p4 = t & 7;          // phase A: thread owns (ci=c_l, p = p4*4..p4*4+3)
    f32x4 in4[16];
    for (int bp = 0; bp < 16; bp++)
        in4[bp] = *(const f32x4*)(x + (size_t)bp * DV + (size_t)(c0 + c_l) * HW_ + p0 + p4 * 4);
    __syncthreads();
    for (int b = 0; b < 16; b++) {
        f32x4 acc = (f32x4){0.f, 0.f, 0.f, 0.f};
        for (int bp = 0; bp < 16; bp++) {
            float wgt = Ms[b * 16 + bp];
            acc += wgt * in4[bp];
        }
        for (int e = 0; e < 4; e++) T[b][p4 * 4 + e][c_l] = f2bf(acc[e]);
    }
    __syncthreads();
    int p_l = t >> 3, cq = t & 7;          // phase B: fragment-layout writeout
    int p = p0 + p_l;
    int c = c0 + cq * 4;
    size_t dst = (size_t)(p >> 4) * 4096 + (size_t)(c >> 3) * 128 + (p & 15) * 8 + (c & 7);
    for (int b = 0; b < 16; b++) {
        u16x4 v = *(const u16x4*)&T[b][p_l][cq * 4];
        *(u16x4*)(Xm + (size_t)b * DV + dst) = v;
    }
}

// ---------------- v GEMM + bias + residual: NO LDS, no barriers — pre-fragmented operands.
// BM=128 (wave 64m x 32n), BN=64, full K=256 unrolled. Frag load = base + lane*16B (coalesced 1KB/wave).
__global__ __launch_bounds__(256) void k_gemm_v_res(const unsigned short* __restrict__ Wvf,
                                                    const unsigned short* __restrict__ Xmf,
                                                    const float* __restrict__ bv,
                                                    const float* __restrict__ MmRs,
                                                    const float* __restrict__ x,
                                                    float* __restrict__ out) {
    int b  = blockIdx.z;
    int m0 = blockIdx.y * 128;
    int n0 = blockIdx.x * 64;
    int t = threadIdx.x;
    int lane = t & 63, wid = t >> 6;
    int wm = wid >> 1, wn = wid & 1;          // wave tile: 64m x 32n
    int lr = lane & 15, kg = lane >> 4;

    const unsigned short* Ab = Wvf + (size_t)((m0 >> 4) + wm * 4) * 4096 + lane * 8;
    const unsigned short* Bb = Xmf + (size_t)b * DV + (size_t)((n0 >> 4) + wn * 2) * 4096 + lane * 8;

    f32x4 acc[4][2];
    for (int mi = 0; mi < 4; mi++)
        for (int ni = 0; ni < 2; ni++) acc[mi][ni] = (f32x4){0.f, 0.f, 0.f, 0.f};

    #pragma unroll 4
    for (int kk = 0; kk < 8; kk++) {
        bf16x8 a[4], bb[2];
        for (int mi = 0; mi < 4; mi++) a[mi]  = *(const bf16x8*)(Ab + (size_t)mi * 4096 + kk * 512);
        for (int ni = 0; ni < 2; ni++) bb[ni] = *(const bf16x8*)(Bb + (size_t)ni * 4096 + kk * 512);
        for (int mi = 0; mi < 4; mi++)
            for (int ni = 0; ni < 2; ni++)
                acc[mi][ni] = __builtin_amdgcn_mfma_f32_16x16x32_bf16(a[mi], bb[ni], acc[mi][ni], 0, 0, 0);
    }

    float rs_b = MmRs[256 + b];
    for (int mi = 0; mi < 4; mi++) {
        int mbase = m0 + wm * 64 + mi * 16 + kg * 4;
        for (int i = 0; i < 4; i++) {
            int m = mbase + i;
            float bias = rs_b * bv[m];
            size_t rowoff = (size_t)b * DV + (size_t)m * HW_;
            for (int ni = 0; ni < 2; ni++) {
                int n = n0 + wn * 32 + ni * 16 + lr;
                out[rowoff + n] = acc[mi][ni][i] + bias + x[rowoff + n];
            }
        }
    }
}

extern "C" void kernel_launch(void* const* d_in, const int* in_sizes, int n_in,
                              void* d_out, int out_size, void* d_ws, size_t ws_size,
                              hipStream_t stream) {
    (void)in_sizes; (void)n_in; (void)out_size; (void)ws_size;
    const float* x     = (const float*)d_in[0];
    const float* wq    = (const float*)d_in[1];
    const float* bq    = (const float*)d_in[2];
    const float* wk    = (const float*)d_in[3];
    const float* bk    = (const float*)d_in[4];
    const float* wv    = (const float*)d_in[5];
    const float* bv    = (const float*)d_in[6];
    const float* gamma = (const float*)d_in[7];

    char* ws = (char*)d_ws;
    // ws layout (bytes): Wh 32768 | Wl 32768 | Wv_frag 131072 | QF 8388608 | KF 8388608 | Xm_frag 33554432
    // Aliases (lifetime-disjoint): Mm@0 (Wh dead after qk); Sp@Xm-start (dead before mix writes).
    unsigned short* Wh = (unsigned short*)(ws + 0);
    unsigned short* Wl = (unsigned short*)(ws + 32768);
    unsigned short* Wv = (unsigned short*)(ws + 65536);
    float*          QF = (float*)(ws + 196608);
    float*          KF = (float*)(ws + 8585216);
    unsigned short* Xm = (unsigned short*)(ws + 16973824);   // 33554432 bytes -> total 50528256
    float*          Sp = (float*)(ws + 16973824);            // 128 KB, aliases Xm (ordered before)
    float*          Mm = (float*)(ws + 0);                   // aliases Wh (dead by then)
    float*          vo = (float*)d_out;

    k_pack       <<<320, 256, 0, stream>>>(wq, wk, wv, Wh, Wl, Wv);
    k_gemm_qk    <<<dim3(32, 16), 256, 0, stream>>>(Wh, Wl, x, bq, bk, QF, KF);
    k_scores2    <<<256, 256, 0, stream>>>(QF, KF, Sp);
    k_softmax2   <<<1, 128, 0, stream>>>(Sp, gamma, Mm);
    k_mix        <<<dim3(128, 8), 256, 0, stream>>>(Mm, x, Xm);
    k_gemm_v_res <<<dim3(64, 2, 16), 256, 0, stream>>>(Wv, Xm, bv, Mm, x, vo);
}

// Round 5
// 91.108 us; speedup vs baseline: 1.0953x; 1.0141x over previous
//
#include <hip/hip_runtime.h>

#define B_   16
#define C_   256
#define HW_  4096
#define DQK  131072     // 32*4096, q/k feature dim per batch
#define DV   1048576    // 256*4096, v feature dim per batch

using bf16x8  = __attribute__((ext_vector_type(8))) __bf16;
using ushort8 = __attribute__((ext_vector_type(8))) unsigned short;
using u16x4   = __attribute__((ext_vector_type(4))) unsigned short;
using f32x4   = __attribute__((ext_vector_type(4))) float;

static __device__ __forceinline__ unsigned short f2bf(float f) {
    union { float f; unsigned u; } v; v.f = f;
    unsigned r = v.u + 0x7FFFu + ((v.u >> 16) & 1u);
    return (unsigned short)(r >> 16);
}
static __device__ __forceinline__ float bf2f(unsigned short h) {
    union { unsigned u; float f; } v; v.u = ((unsigned)h) << 16;
    return v.f;
}

// ---------------- pack weights:
// WhF/WlF = hi/lo split of [wq;wk] (64x256) in A-FRAGMENT layout:
//   addr(m,c) = (m>>4)*4096 + (c>>3)*128 + (m&15)*8 + (c&7)
// WvF bf16 (256x256) pre-fragmented (same formula).
__global__ __launch_bounds__(256) void k_pack(const float* wq, const float* wk, const float* wv,
                                              unsigned short* WhF, unsigned short* WlF, unsigned short* WvF) {
    int idx = blockIdx.x * 256 + threadIdx.x;   // 81920 total
    if (idx < 16384) {
        int i = idx;                            // destination-linear
        int mt = i >> 12, cg = (i >> 7) & 31, ml = (i >> 3) & 15, cl = i & 7;
        int m = mt * 16 + ml, c = cg * 8 + cl;
        float f = (m < 32) ? wq[m * 256 + c] : wk[(m - 32) * 256 + c];
        unsigned short hi = f2bf(f);
        WhF[i] = hi;
        WlF[i] = f2bf(f - bf2f(hi));
    } else {
        int i = idx - 16384;                    // destination-linear (coalesced writes)
        int mt = i >> 12, kt = (i >> 7) & 31, lr = (i >> 3) & 15, j = i & 7;
        int m = mt * 16 + lr, c = kt * 8 + j;
        WvF[i] = f2bf(wv[m * 256 + c]);
    }
}

// ---------------- qk GEMM, split-bf16, NO LDS, no barriers.
// Wave tile 32m x 32n; wm: 0=q rows, 1=k rows. B-frags built in-register from direct x loads.
__global__ __launch_bounds__(256) void k_gemm_qk(const unsigned short* __restrict__ WhF,
                                                 const unsigned short* __restrict__ WlF,
                                                 const float* __restrict__ x,
                                                 const float* __restrict__ bq, const float* __restrict__ bk,
                                                 float* __restrict__ QF, float* __restrict__ KF) {
    int b  = blockIdx.y;
    int n0 = blockIdx.x * 64;
    int t = threadIdx.x;
    int lane = t & 63, wid = t >> 6;
    int wm = wid & 1, wn = wid >> 1;            // wm: q/k half; wn: n sub-tile
    int lr = lane & 15, kg = lane >> 4;

    const float* xb = x + (size_t)b * DV;
    const unsigned short* Ah0 = WhF + (size_t)(wm * 2) * 4096 + lane * 8;
    const unsigned short* Al0 = WlF + (size_t)(wm * 2) * 4096 + lane * 8;

    f32x4 acc[2][2];
    for (int mi = 0; mi < 2; mi++)
        for (int ni = 0; ni < 2; ni++) acc[mi][ni] = (f32x4){0.f, 0.f, 0.f, 0.f};

    for (int kk = 0; kk < 8; kk++) {
        bf16x8 ah[2], al[2];
        for (int mi = 0; mi < 2; mi++) {
            ah[mi] = *(const bf16x8*)(Ah0 + (size_t)mi * 4096 + kk * 512);
            al[mi] = *(const bf16x8*)(Al0 + (size_t)mi * 4096 + kk * 512);
        }
        bf16x8 bh[2], bl[2];
        int cbase = kk * 32 + kg * 8;
        for (int ni = 0; ni < 2; ni++) {
            const float* xp = xb + (size_t)cbase * HW_ + n0 + wn * 32 + ni * 16 + lr;
            #pragma unroll
            for (int j = 0; j < 8; j++) {
                float v = xp[(size_t)j * HW_];
                __bf16 h = (__bf16)v;
                bh[ni][j] = h;
                bl[ni][j] = (__bf16)(v - (float)h);
            }
        }
        for (int mi = 0; mi < 2; mi++)
            for (int ni = 0; ni < 2; ni++) {
                acc[mi][ni] = __builtin_amdgcn_mfma_f32_16x16x32_bf16(ah[mi], bh[ni], acc[mi][ni], 0, 0, 0);
                acc[mi][ni] = __builtin_amdgcn_mfma_f32_16x16x32_bf16(ah[mi], bl[ni], acc[mi][ni], 0, 0, 0);
                acc[mi][ni] = __builtin_amdgcn_mfma_f32_16x16x32_bf16(al[mi], bh[ni], acc[mi][ni], 0, 0, 0);
            }
    }

    float* dst = (wm == 0) ? QF : KF;
    const float* bias = (wm == 0) ? bq : bk;
    for (int mi = 0; mi < 2; mi++) {
        int mq0 = mi * 16 + kg * 4;             // row within the 32-row q or k block
        for (int i = 0; i < 4; i++) {
            int mq = mq0 + i;
            float bs = bias[mq];
            for (int ni = 0; ni < 2; ni++) {
                int n = n0 + wn * 32 + ni * 16 + lr;
                dst[(size_t)b * DQK + (size_t)mq * HW_ + n] = acc[mi][ni][i] + bs;
            }
        }
    }
}

// ---------------- scores v2: 256 blocks, each owns a 512-elem d-slice for ALL 16 batches.
__global__ __launch_bounds__(256) void k_scores2(const float* __restrict__ QF, const float* __restrict__ KF,
                                                 float* __restrict__ Sp) {
    __shared__ float Ql[16][520], Kl[16][520];   // +8 pad: spreads banks across b
    int s = blockIdx.x;                          // 0..255 : d-slice [s*512, s*512+512)
    int m = s >> 3, off = (s & 7) * 512;
    int t = threadIdx.x;
    for (int b = 0; b < 16; b++) {
        const float* qs = QF + (size_t)b * DQK + (size_t)m * HW_ + off;
        const float* ks = KF + (size_t)b * DQK + (size_t)m * HW_ + off;
        Ql[b][t]       = qs[t];
        Ql[b][t + 256] = qs[t + 256];
        Kl[b][t]       = ks[t];
        Kl[b][t + 256] = ks[t + 256];
    }
    __syncthreads();
    int p = t >> 1, h = t & 1;                   // 2 threads per pair
    int b = p >> 3, j = p & 7;
    int hb = b >> 2, wb = b & 3;
    int bp = (j < 4) ? (j * 4 + wb) : (hb * 4 + (j - 4));
    const f32x4* q4 = (const f32x4*)&Ql[b][h * 256];
    const f32x4* k4 = (const f32x4*)&Kl[bp][h * 256];
    f32x4 a4 = (f32x4){0.f, 0.f, 0.f, 0.f};
    for (int i = 0; i < 64; i++) a4 += q4[i] * k4[i];
    float sres = a4[0] + a4[1] + a4[2] + a4[3];
    sres += __shfl_xor(sres, 1);
    if (h == 0) Sp[(size_t)p * 256 + s] = sres;  // layout [pair][slice]
}

// ---------------- reduce slices + softmax + fold gamma -> M [0..255] + rowsum [256..271]
__global__ void k_softmax2(const float* __restrict__ Sp, const float* __restrict__ gamma,
                           float* __restrict__ Mm) {
    __shared__ float SS[128];
    int t = threadIdx.x;                         // 128 threads
    const f32x4* s4 = (const f32x4*)(Sp + (size_t)t * 256);
    f32x4 a = (f32x4){0.f, 0.f, 0.f, 0.f};
    for (int i = 0; i < 64; i++) a += s4[i];
    SS[t] = a[0] + a[1] + a[2] + a[3];
    __syncthreads();
    if (t < 16) {
        int b = t, h = b >> 2, w = b & 3;
        float e[8];
        for (int j = 0; j < 8; j++) e[j] = SS[b * 8 + j];
        e[h] = -INFINITY;                        // masked diagonal of eH
        float mx = e[0];
        for (int j = 1; j < 8; j++) mx = fmaxf(mx, e[j]);
        float aa[8], sum = 0.f;
        for (int j = 0; j < 8; j++) { aa[j] = expf(e[j] - mx); sum += aa[j]; }
        float inv = 1.0f / sum;
        float g = gamma[0];
        float row[16];
        for (int c = 0; c < 16; c++) row[c] = 0.f;
        for (int gg = 0; gg < 4; gg++) if (gg != h) row[gg * 4 + w] += aa[gg] * inv;     // eH partners
        for (int gg = 0; gg < 4; gg++) row[h * 4 + gg] += aa[4 + gg] * inv;              // eW partners
        for (int c = 0; c < 16; c++) Mm[b * 16 + c] = row[c] * g;
        Mm[256 + b] = g;                         // rowsum of M (softmax rows sum to 1)
    }
}

// ---------------- mix + transpose + convert, PRE-FRAGMENTED output, 7-sparse M rows.
// Xm addr(b,p,c) = b*DV + (p>>4)*4096 + (c>>3)*128 + (p&15)*8 + (c&7); value = sum_bp M[b][bp]*x[bp][c][p]
__global__ __launch_bounds__(256) void k_mix(const float* __restrict__ Mm, const float* __restrict__ x,
                                             unsigned short* __restrict__ Xm) {
    __shared__ float Ms[256];
    __shared__ unsigned short T[16][32][36];     // [b][p][c]
    int t = threadIdx.x;
    int p0 = blockIdx.x * 32, c0 = blockIdx.y * 32;
    Ms[t] = Mm[t];

    int c_l = t >> 3, p4 = t & 7;          // phase A: thread owns (ci=c_l, p = p4*4..p4*4+3)
    f32x4 in4[16];
    for (int bp = 0; bp < 16; bp++)
        in4[bp] = *(const f32x4*)(x + (size_t)bp * DV + (size_t)(c0 + c_l) * HW_ + p0 + p4 * 4);
    __syncthreads();
    for (int b = 0; b < 16; b++) {
        int h = b >> 2, w = b & 3;
        f32x4 acc = (f32x4){0.f, 0.f, 0.f, 0.f};
        #pragma unroll
        for (int g = 0; g < 4; g++) {          // 7 structural nonzeros per row
            if (g != h) acc += Ms[b * 16 + g * 4 + w] * in4[g * 4 + w];
            acc += Ms[b * 16 + h * 4 + g] * in4[h * 4 + g];
        }
        for (int e = 0; e < 4; e++) T[b][p4 * 4 + e][c_l] = f2bf(acc[e]);
    }
    __syncthreads();
    int p_l = t >> 3, cq = t & 7;          // phase B: fragment-layout writeout
    int p = p0 + p_l;
    int c = c0 + cq * 4;
    size_t dst = (size_t)(p >> 4) * 4096 + (size_t)(c >> 3) * 128 + (p & 15) * 8 + (c & 7);
    for (int b = 0; b < 16; b++) {
        u16x4 v = *(const u16x4*)&T[b][p_l][cq * 4];
        *(u16x4*)(Xm + (size_t)b * DV + dst) = v;
    }
}

// ---------------- v GEMM + bias + residual: NO LDS, no barriers — pre-fragmented operands.
// BM=128 (wave 64m x 32n), BN=64, full K=256 unrolled. Frag load = base + lane*16B (coalesced 1KB/wave).
__global__ __launch_bounds__(256) void k_gemm_v_res(const unsigned short* __restrict__ Wvf,
                                                    const unsigned short* __restrict__ Xmf,
                                                    const float* __restrict__ bv,
                                                    const float* __restrict__ MmRs,
                                                    const float* __restrict__ x,
                                                    float* __restrict__ out) {
    int b  = blockIdx.z;
    int m0 = blockIdx.y * 128;
    int n0 = blockIdx.x * 64;
    int t = threadIdx.x;
    int lane = t & 63, wid = t >> 6;
    int wm = wid >> 1, wn = wid & 1;          // wave tile: 64m x 32n
    int lr = lane & 15, kg = lane >> 4;

    const unsigned short* Ab = Wvf + (size_t)((m0 >> 4) + wm * 4) * 4096 + lane * 8;
    const unsigned short* Bb = Xmf + (size_t)b * DV + (size_t)((n0 >> 4) + wn * 2) * 4096 + lane * 8;

    f32x4 acc[4][2];
    for (int mi = 0; mi < 4; mi++)
        for (int ni = 0; ni < 2; ni++) acc[mi][ni] = (f32x4){0.f, 0.f, 0.f, 0.f};

    #pragma unroll 4
    for (int kk = 0; kk < 8; kk++) {
        bf16x8 a[4], bb[2];
        for (int mi = 0; mi < 4; mi++) a[mi]  = *(const bf16x8*)(Ab + (size_t)mi * 4096 + kk * 512);
        for (int ni = 0; ni < 2; ni++) bb[ni] = *(const bf16x8*)(Bb + (size_t)ni * 4096 + kk * 512);
        for (int mi = 0; mi < 4; mi++)
            for (int ni = 0; ni < 2; ni++)
                acc[mi][ni] = __builtin_amdgcn_mfma_f32_16x16x32_bf16(a[mi], bb[ni], acc[mi][ni], 0, 0, 0);
    }

    float rs_b = MmRs[256 + b];
    for (int mi = 0; mi < 4; mi++) {
        int mbase = m0 + wm * 64 + mi * 16 + kg * 4;
        for (int i = 0; i < 4; i++) {
            int m = mbase + i;
            float bias = rs_b * bv[m];
            size_t rowoff = (size_t)b * DV + (size_t)m * HW_;
            for (int ni = 0; ni < 2; ni++) {
                int n = n0 + wn * 32 + ni * 16 + lr;
                out[rowoff + n] = acc[mi][ni][i] + bias + x[rowoff + n];
            }
        }
    }
}

extern "C" void kernel_launch(void* const* d_in, const int* in_sizes, int n_in,
                              void* d_out, int out_size, void* d_ws, size_t ws_size,
                              hipStream_t stream) {
    (void)in_sizes; (void)n_in; (void)out_size; (void)ws_size;
    const float* x     = (const float*)d_in[0];
    const float* wq    = (const float*)d_in[1];
    const float* bq    = (const float*)d_in[2];
    const float* wk    = (const float*)d_in[3];
    const float* bk    = (const float*)d_in[4];
    const float* wv    = (const float*)d_in[5];
    const float* bv    = (const float*)d_in[6];
    const float* gamma = (const float*)d_in[7];

    char* ws = (char*)d_ws;
    // ws layout (bytes): WhF 32768 | WlF 32768 | WvF 131072 | QF 8388608 | KF 8388608 | Xm_frag 33554432
    // Aliases (lifetime-disjoint): Mm@0 (WhF dead after qk); Sp@Xm-start (dead before mix writes).
    unsigned short* WhF = (unsigned short*)(ws + 0);
    unsigned short* WlF = (unsigned short*)(ws + 32768);
    unsigned short* WvF = (unsigned short*)(ws + 65536);
    float*          QF  = (float*)(ws + 196608);
    float*          KF  = (float*)(ws + 8585216);
    unsigned short* Xm  = (unsigned short*)(ws + 16973824);  // 33554432 bytes -> total 50528256
    float*          Sp  = (float*)(ws + 16973824);           // 128 KB, aliases Xm (ordered before)
    float*          Mm  = (float*)(ws + 0);                  // aliases WhF (dead by then)
    float*          vo  = (float*)d_out;

    k_pack       <<<320, 256, 0, stream>>>(wq, wk, wv, WhF, WlF, WvF);
    k_gemm_qk    <<<dim3(64, 16), 256, 0, stream>>>(WhF, WlF, x, bq, bk, QF, KF);
    k_scores2    <<<256, 256, 0, stream>>>(QF, KF, Sp);
    k_softmax2   <<<1, 128, 0, stream>>>(Sp, gamma, Mm);
    k_mix        <<<dim3(128, 8), 256, 0, stream>>>(Mm, x, Xm);
    k_gemm_v_res <<<dim3(64, 2, 16), 256, 0, stream>>>(WvF, Xm, bv, Mm, x, vo);
}